// Round 1
// baseline (208.163 us; speedup 1.0000x reference)
//
#include <hip/hip_runtime.h>

// out[t, :] = sum_k scores[t*K+k] * moe[slots[t*K+k], :]
// One block per token; float4 (16 B/lane) vectorized loads/stores.
// HIDDEN=2048 floats = 512 float4 -> 2 per thread at block=256.
__global__ __launch_bounds__(256) void moe_gather_kernel(
    const float* __restrict__ moe,     // [total_slots, hidden]
    const float* __restrict__ scores,  // [total_slots]
    const int*   __restrict__ slots,   // [total_slots]
    float*       __restrict__ out,     // [n_tokens, hidden]
    int hidden, int top_k) {
    const int t   = blockIdx.x;
    const int tid = threadIdx.x;
    const int nvec = hidden >> 2;  // float4 count per row

    // Hoist slot/score loads (wave-uniform; scalar-cached)
    // top_k is small (2); cap at 8 for register safety.
    float w[8];
    const float4* rows[8];
    const int K = top_k > 8 ? 8 : top_k;
    for (int k = 0; k < K; ++k) {
        const int s = slots[(size_t)t * top_k + k];
        w[k] = scores[(size_t)t * top_k + k];
        rows[k] = (const float4*)(moe + (size_t)s * hidden);
    }

    float4* orow = (float4*)(out + (size_t)t * hidden);
    for (int v = tid; v < nvec; v += blockDim.x) {
        float4 acc = make_float4(0.f, 0.f, 0.f, 0.f);
        for (int k = 0; k < K; ++k) {
            float4 x = rows[k][v];
            acc.x += w[k] * x.x;
            acc.y += w[k] * x.y;
            acc.z += w[k] * x.z;
            acc.w += w[k] * x.w;
        }
        orow[v] = acc;
    }
}

extern "C" void kernel_launch(void* const* d_in, const int* in_sizes, int n_in,
                              void* d_out, int out_size, void* d_ws, size_t ws_size,
                              hipStream_t stream) {
    const float* moe    = (const float*)d_in[0];
    const float* scores = (const float*)d_in[1];
    const int*   slots  = (const int*)d_in[2];
    float* out = (float*)d_out;

    const int total_slots = in_sizes[1];            // 16384
    const int hidden      = in_sizes[0] / total_slots;  // 2048
    const int n_tokens    = out_size / hidden;      // 8192
    const int top_k       = total_slots / n_tokens; // 2

    moe_gather_kernel<<<n_tokens, 256, 0, stream>>>(moe, scores, slots, out,
                                                    hidden, top_k);
}